// Round 13
// baseline (4269.590 us; speedup 1.0000x reference)
//
#include <hip/hip_runtime.h>
#include <math.h>

#define Bq_ 4
#define Lq_ 4096
#define Dq_ 2048
#define Mq_ 16384
#define NW_ 4096
#define DQK_ 2048
#define NSLOT 32
#define BM_ 256
#define BN_ 128
#define NSEG 16
#define SEGLEN 256
#define BUFSZ 66560    // A 264*128 + B 256*128 (single buffer)
#define BOFF_ 33792

typedef short s8v __attribute__((ext_vector_type(8)));
typedef float f4v __attribute__((ext_vector_type(4)));

#define GLDS16(g, l) __builtin_amdgcn_global_load_lds( \
    (const __attribute__((address_space(1))) unsigned int*)(g), \
    (__attribute__((address_space(3))) unsigned int*)(l), 16, 0, 0)

__device__ __forceinline__ void bf16split(float x, unsigned short& h, unsigned short& l) {
    unsigned u = __float_as_uint(x);
    unsigned hb = (u + 0x7FFFu + ((u >> 16) & 1u)) & 0xFFFF0000u;
    float fh = __uint_as_float(hb);
    float r = x - fh;
    unsigned ur = __float_as_uint(r);
    unsigned lb = (ur + 0x7FFFu + ((ur >> 16) & 1u)) >> 16;
    h = (unsigned short)(hb >> 16);
    l = (unsigned short)lb;
}

// ---------------------------------------------------------------------------
__global__ __launch_bounds__(256) void split_kernel(const float* __restrict__ in,
                                                    unsigned short* __restrict__ hi,
                                                    unsigned short* __restrict__ lo,
                                                    int n4) {
    int stride = gridDim.x * 256;
    for (int i = blockIdx.x * 256 + threadIdx.x; i < n4; i += stride) {
        float4 v = ((const float4*)in)[i];
        float vv[4] = {v.x, v.y, v.z, v.w};
        unsigned short hh[4], ll[4];
#pragma unroll
        for (int j = 0; j < 4; ++j) bf16split(vv[j], hh[j], ll[j]);
        ushort4 h4 = make_ushort4(hh[0], hh[1], hh[2], hh[3]);
        ushort4 l4 = make_ushort4(ll[0], ll[1], ll[2], ll[3]);
        ((ushort4*)hi)[i] = h4;
        ((ushort4*)lo)[i] = l4;
    }
}

// W [2048][4096] f32 -> WhiT/WloT [4096][2048] bf16 (transposed + split)
__global__ __launch_bounds__(256) void wsplitT_kernel(const float* __restrict__ W,
                                                      unsigned short* __restrict__ hiT,
                                                      unsigned short* __restrict__ loT) {
    __shared__ float tile[64][65];
    int k0 = blockIdx.x * 64, n0 = blockIdx.y * 64;
    int tid = threadIdx.x;
#pragma unroll
    for (int e = 0; e < 16; ++e) {
        int idx = e * 256 + tid;
        int r = idx >> 6, j = idx & 63;
        tile[r][j] = W[(size_t)(k0 + r) * NW_ + n0 + j];
    }
    __syncthreads();
#pragma unroll
    for (int e = 0; e < 16; ++e) {
        int idx = e * 256 + tid;
        int nn = idx >> 6, kk = idx & 63;
        unsigned short h, l;
        bf16split(tile[kk][nn], h, l);
        size_t o = (size_t)(n0 + nn) * DQK_ + k0 + kk;
        hiT[o] = h;
        loT[o] = l;
    }
}

// ---------------------------------------------------------------------------
__global__ __launch_bounds__(256) void wqs_kernel(const float* __restrict__ W,
                                                  const float* __restrict__ s,
                                                  float* __restrict__ w) {
    int d = blockIdx.x;
    int tid = threadIdx.x;
    float acc = 0.f;
    const float* row = W + (size_t)d * NW_;
    for (int j = tid; j < DQK_; j += 256) acc += row[j] * s[j];
    __shared__ float red[256];
    red[tid] = acc;
    __syncthreads();
    for (int off = 128; off > 0; off >>= 1) {
        if (tid < off) red[tid] += red[tid + off];
        __syncthreads();
    }
    if (tid == 0) w[d] = red[0];
}

__global__ __launch_bounds__(256) void l0_kernel(const float* __restrict__ tokens,
                                                 const float* __restrict__ s,
                                                 const float* __restrict__ w,
                                                 float* __restrict__ c0,
                                                 float* __restrict__ snorm) {
    int b = blockIdx.x;
    int tid = threadIdx.x;
    float acc = 0.f;
    if (b < Bq_) {
        const float* t = tokens + (size_t)b * Lq_ * Dq_;
        for (int dd = tid; dd < Dq_; dd += 256) acc += t[dd] * w[dd];
    } else {
        for (int jj = tid; jj < DQK_; jj += 256) acc += s[jj] * s[jj];
    }
    __shared__ float red[256];
    red[tid] = acc;
    __syncthreads();
    for (int off = 128; off > 0; off >>= 1) {
        if (tid < off) red[tid] += red[tid + off];
        __syncthreads();
    }
    if (tid == 0) {
        if (b < Bq_) c0[b] = red[0];
        else snorm[0] = red[0];
    }
}

// ---------------------------------------------------------------------------
// bf16x3 MFMA GEMM (256x128, full K, BK=32, hi|lo-packed rows) with SINGLE
// LDS buffer so 2 blocks co-reside per CU (4 waves/SIMD): one block's
// stage+drain hides under the other block's MFMA phase (m114 overlap).
// id = mt*16 + nt : XCD x owns nt in {x, x+8}.
__global__ __launch_bounds__(512, 4) void gemm_kernel(const unsigned short* __restrict__ Thi,
                                                      const unsigned short* __restrict__ Tlo,
                                                      const unsigned short* __restrict__ Whi,
                                                      const unsigned short* __restrict__ Wlo,
                                                      float* __restrict__ pa,
                                                      float* __restrict__ pkn,
                                                      float* __restrict__ pcn) {
    extern __shared__ char smc[];

    int id = blockIdx.x;
    int nt = id & 15;
    int mt = id >> 4;
    int r0 = mt * BM_;
    int c0 = nt * BN_;
    int tid = threadIdx.x;
    int lane = tid & 63, w = tid >> 6;
    int wm = w >> 1, wn = w & 1;
    int lr = lane & 15, lg = lane >> 4;

    // ---- staging addresses (row = 128B = [hi 32bf16 | lo 32bf16], XOR chunk swz)
    int rl = tid >> 3;            // row within 64-row call block
    int ch = tid & 7;             // phys chunk
    int s = ch ^ (rl & 7);        // logical source chunk
    const unsigned short* aptr = (s < 4) ? Thi : Tlo;
    const unsigned short* bptr = (s < 4) ? Whi : Wlo;
    int ako = (s & 3) * 8;
    int aoff[4], boff[4];
#pragma unroll
    for (int i = 0; i < 4; ++i) {
        int g = r0 - 1 + i * 64 + rl;
        g = g < 0 ? 0 : (g > Mq_ - 1 ? Mq_ - 1 : g);
        aoff[i] = g * Dq_ + ako;
    }
#pragma unroll
    for (int i = 0; i < 4; ++i) {
        int j = i * 64 + rl;
        int wr = j < 128 ? c0 + j : DQK_ + c0 + (j - 128);
        boff[i] = wr * DQK_ + ako;
    }
    // partial A call (rows 256..263, wave 0 only)
    int rlX = 256 + (lane >> 3);
    int sX = (lane & 7) ^ ((lane >> 3) & 7);
    const unsigned short* aptrX = (sX < 4) ? Thi : Tlo;
    int gX = r0 - 1 + rlX;
    gX = gX > Mq_ - 1 ? Mq_ - 1 : gX;
    int aoffX = gX * Dq_ + (sX & 3) * 8;

    // ---- ds read byte-offsets (hi; lo = ^64)
    int aq_ad[4], ak_ad[4], bq_ad[4], bk_ad[4];
#pragma unroll
    for (int rf = 0; rf < 4; ++rf) {
        int rq = wm * 64 + rf * 16 + lr + 1;
        int rk = rq - 1;
        aq_ad[rf] = rq * 128 + ((lg ^ (rq & 7)) * 16);
        ak_ad[rf] = rk * 128 + ((lg ^ (rk & 7)) * 16);
    }
#pragma unroll
    for (int cf = 0; cf < 4; ++cf) {
        int rbq = wn * 64 + cf * 16 + lr;
        int rbk = rbq + 128;
        bq_ad[cf] = rbq * 128 + ((lg ^ (rbq & 7)) * 16);
        bk_ad[cf] = rbk * 128 + ((lg ^ (rbk & 7)) * 16);
    }

    f4v accq[4][4], acck[4][4];
#pragma unroll
    for (int rf = 0; rf < 4; ++rf)
#pragma unroll
        for (int cf = 0; cf < 4; ++cf) {
            accq[rf][cf] = (f4v){0.f, 0.f, 0.f, 0.f};
            acck[rf][cf] = (f4v){0.f, 0.f, 0.f, 0.f};
        }

#define STAGE(k0e)                                                          \
    {                                                                       \
        char* bA = smc;                                                     \
        char* bB = smc + BOFF_;                                             \
        _Pragma("unroll")                                                   \
        for (int i = 0; i < 4; ++i)                                         \
            GLDS16(aptr + aoff[i] + (k0e), bA + (i * 64 + w * 8) * 128);    \
        if (w == 0)                                                         \
            GLDS16(aptrX + aoffX + (k0e), bA + 256 * 128);                  \
        _Pragma("unroll")                                                   \
        for (int i = 0; i < 4; ++i)                                         \
            GLDS16(bptr + boff[i] + (k0e), bB + (i * 64 + w * 8) * 128);    \
    }

    for (int kt = 0; kt < 64; ++kt) {
        STAGE(kt * 32);
        __syncthreads();                       // drain stage, buffer ready

        const char* bA = smc;
        const char* bB = smc + BOFF_;
        s8v aqh[4], aql[4], akh[4], akl[4];
#pragma unroll
        for (int rf = 0; rf < 4; ++rf) {
            aqh[rf] = *(const s8v*)(bA + aq_ad[rf]);
            aql[rf] = *(const s8v*)(bA + (aq_ad[rf] ^ 64));
            akh[rf] = *(const s8v*)(bA + ak_ad[rf]);
            akl[rf] = *(const s8v*)(bA + (ak_ad[rf] ^ 64));
        }
#pragma unroll
        for (int cf = 0; cf < 4; ++cf) {
            s8v bqh = *(const s8v*)(bB + bq_ad[cf]);
            s8v bql = *(const s8v*)(bB + (bq_ad[cf] ^ 64));
            s8v bkh = *(const s8v*)(bB + bk_ad[cf]);
            s8v bkl = *(const s8v*)(bB + (bk_ad[cf] ^ 64));
#pragma unroll
            for (int rf = 0; rf < 4; ++rf) {
                accq[rf][cf] = __builtin_amdgcn_mfma_f32_16x16x32_bf16(aqh[rf], bqh, accq[rf][cf], 0, 0, 0);
                accq[rf][cf] = __builtin_amdgcn_mfma_f32_16x16x32_bf16(aqh[rf], bql, accq[rf][cf], 0, 0, 0);
                accq[rf][cf] = __builtin_amdgcn_mfma_f32_16x16x32_bf16(aql[rf], bqh, accq[rf][cf], 0, 0, 0);
                acck[rf][cf] = __builtin_amdgcn_mfma_f32_16x16x32_bf16(akh[rf], bkh, acck[rf][cf], 0, 0, 0);
                acck[rf][cf] = __builtin_amdgcn_mfma_f32_16x16x32_bf16(akh[rf], bkl, acck[rf][cf], 0, 0, 0);
                acck[rf][cf] = __builtin_amdgcn_mfma_f32_16x16x32_bf16(akl[rf], bkh, acck[rf][cf], 0, 0, 0);
            }
        }
        __syncthreads();                       // all reads done before next stage
    }
#undef STAGE

    size_t o = (size_t)(nt * 2 + wn) * Mq_;
#pragma unroll
    for (int rf = 0; rf < 4; ++rf) {
        int rbase = r0 + wm * 64 + rf * 16 + lg * 4;
#pragma unroll
        for (int jj = 0; jj < 4; ++jj) {
            float sq = 0.f, sk = 0.f, sc = 0.f;
#pragma unroll
            for (int cf = 0; cf < 4; ++cf) {
                float q = accq[rf][cf][jj];
                float k = acck[rf][cf][jj];
                sq = fmaf(q, q, sq);
                sk = fmaf(k, k, sk);
                sc = fmaf(q, k, sc);
            }
#pragma unroll
            for (int m = 1; m < 16; m <<= 1) {
                sq += __shfl_xor(sq, m);
                sk += __shfl_xor(sk, m);
                sc += __shfl_xor(sc, m);
            }
            if (lr == 0) {
                int r = rbase + jj;
                pa[o + r] = sq;   // ||q_r||^2 partial
                pcn[o + r] = sc;  // q_r . k_{r-1} partial
                pkn[o + r] = sk;  // ||k_{r-1}||^2 partial
            }
        }
    }
}

// ---------------------------------------------------------------------------
__global__ __launch_bounds__(256) void rowstat_kernel(const float* __restrict__ pa,
                                                      const float* __restrict__ pkn,
                                                      const float* __restrict__ pcn,
                                                      const float* __restrict__ c0,
                                                      const float* __restrict__ snorm,
                                                      float* __restrict__ probs) {
    int r = blockIdx.x * 256 + threadIdx.x;
    float a = 0.f, bb = 0.f, c = 0.f;
    for (int s = 0; s < NSLOT; ++s) {
        size_t o = (size_t)s * Mq_;
        a += pa[o + r];
        c += pcn[o + r];
        bb += pkn[o + r];
    }
    if ((r & (Lq_ - 1)) == 0) { c = c0[r >> 12]; bb = snorm[0]; }
    float na = fmaxf(sqrtf(a), 1e-8f);
    float nb = fmaxf(sqrtf(bb), 1e-8f);
    float cosv = c / (na * nb);
    probs[r] = (1.f - cosv) * 0.5f;
}

// ---------------------------------------------------------------------------
__global__ __launch_bounds__(256) void pack_kernel(const float* __restrict__ probs,
                                                   int* __restrict__ posArr,
                                                   float* __restrict__ pprob,
                                                   int* __restrict__ cid,
                                                   int* __restrict__ nch,
                                                   float* __restrict__ aux) {
    int b = blockIdx.x;
    int tid = threadIdx.x;
    int base = b * Lq_ + tid * 16;
#pragma unroll
    for (int u = 0; u < 16; ++u) {
        posArr[base + u] = 0;
        pprob[base + u] = 0.f;
    }
    float p[16];
    bool bd[16];
    int c = 0;
#pragma unroll
    for (int u = 0; u < 16; ++u) {
        p[u] = probs[base + u];
        bd[u] = (p[u] > 0.5f) || (tid == 0 && u == 0);
        c += bd[u] ? 1 : 0;
    }
    __shared__ int sc[256];
    sc[tid] = c;
    __syncthreads();
    for (int off = 1; off < 256; off <<= 1) {
        int t = (tid >= off) ? sc[tid - off] : 0;
        __syncthreads();
        sc[tid] += t;
        __syncthreads();
    }
    int idx = sc[tid] - c;
#pragma unroll
    for (int u = 0; u < 16; ++u) {
        if (bd[u]) {
            posArr[b * Lq_ + idx] = tid * 16 + u;
            pprob[b * Lq_ + idx] = p[u];
            idx++;
        }
        cid[base + u] = idx - 1;
    }
    if (tid == 255) nch[b] = sc[255];
    if (b == 0 && tid == 0) aux[0] = 0.0f;
}

// ---------------------------------------------------------------------------
// Segmented gated scan, pass 1: per-segment end state + segment gate product
__global__ __launch_bounds__(256) void segend_kernel(const float* __restrict__ tokens,
                                                     const int* __restrict__ posArr,
                                                     const float* __restrict__ pprob,
                                                     float* __restrict__ hseg,
                                                     float* __restrict__ segGate) {
    int b = blockIdx.z, s = blockIdx.y;
    int ch = blockIdx.x * 256 + threadIdx.x;
    const float* tb = tokens + (size_t)b * Lq_ * Dq_ + ch;
    const int* pos = posArr + b * Lq_ + s * SEGLEN;
    const float* pp = pprob + b * Lq_ + s * SEGLEN;
    float h = 0.f;
    for (int u = 0; u < SEGLEN; ++u) {
        float pv = pp[u];
        int t0 = pos[u];
        h = fmaf(1.f - pv, h, tb[(size_t)t0 * Dq_] * pv);
    }
    hseg[((size_t)b * NSEG + s) * Dq_ + ch] = h;
    __shared__ float g_[256];
    if (blockIdx.x == 0) {
        g_[threadIdx.x] = 1.f - pp[threadIdx.x];
        __syncthreads();
        if (threadIdx.x == 0) {
            float P = 1.f;
            for (int i = 0; i < 256; ++i) P *= g_[i];
            segGate[b * NSEG + s] = P;
        }
    }
}

// pass 2: sequential carry combine across segments
__global__ __launch_bounds__(256) void carry_kernel(const float* __restrict__ hseg,
                                                    const float* __restrict__ segGate,
                                                    float* __restrict__ carryArr) {
    int idx = blockIdx.x * 256 + threadIdx.x;  // 0..8191
    int b = idx >> 11;
    int ch = idx & 2047;
    float carry = 0.f;
#pragma unroll
    for (int s = 0; s < NSEG; ++s) {
        size_t o = ((size_t)b * NSEG + s) * Dq_ + ch;
        carryArr[o] = carry;
        carry = hseg[o] + carry * segGate[b * NSEG + s];
    }
}

// pass 3: re-scan with carry-in, write smoothed
__global__ __launch_bounds__(256) void scan3_kernel(const float* __restrict__ tokens,
                                                    const int* __restrict__ posArr,
                                                    const float* __restrict__ pprob,
                                                    const float* __restrict__ carryArr,
                                                    float* __restrict__ out_sm) {
    int b = blockIdx.z, s = blockIdx.y;
    int ch = blockIdx.x * 256 + threadIdx.x;
    const float* tb = tokens + (size_t)b * Lq_ * Dq_ + ch;
    const int* pos = posArr + b * Lq_ + s * SEGLEN;
    const float* pp = pprob + b * Lq_ + s * SEGLEN;
    float* sm = out_sm + (size_t)b * Lq_ * Dq_ + (size_t)s * SEGLEN * Dq_ + ch;
    float h = carryArr[((size_t)b * NSEG + s) * Dq_ + ch];
    for (int u = 0; u < SEGLEN; ++u) {
        float pv = pp[u];
        int t0 = pos[u];
        h = fmaf(1.f - pv, h, tb[(size_t)t0 * Dq_] * pv);
        sm[(size_t)u * Dq_] = h;
    }
}

// ---------------------------------------------------------------------------
__global__ __launch_bounds__(256) void upsample_kernel(const float* __restrict__ sm,
                                                       const int* __restrict__ cid,
                                                       float* __restrict__ up) {
    int r = blockIdx.x;
    int b = r >> 12;
    int c = cid[r];
    const float* src = sm + ((size_t)b * Lq_ + c) * Dq_;
    float* dst = up + (size_t)r * Dq_;
    int tid = threadIdx.x;
    *(float4*)&dst[tid * 8] = *(const float4*)&src[tid * 8];
    *(float4*)&dst[tid * 8 + 4] = *(const float4*)&src[tid * 8 + 4];
}

// ---------------------------------------------------------------------------
extern "C" void kernel_launch(void* const* d_in, const int* in_sizes, int n_in,
                              void* d_out, int out_size, void* d_ws, size_t ws_size,
                              hipStream_t stream) {
    const float* tokens = (const float*)d_in[0];
    const float* W = (const float*)d_in[1];
    const float* s = (const float*)d_in[2];

    float* out = (float*)d_out;
    float* out_sm = out;
    float* out_up = out + (size_t)Mq_ * Dq_;
    float* out_aux = out + 2 * (size_t)Mq_ * Dq_;

    // bf16 staging buffers live inside d_out (overwritten by final outputs later)
    unsigned short* Thi = (unsigned short*)out_up;                      // 64 MB
    unsigned short* Tlo = (unsigned short*)((char*)out_up + 67108864);  // 64 MB
    unsigned short* WhiT = (unsigned short*)out_sm;                     // 16 MB
    unsigned short* WloT = (unsigned short*)((char*)out_sm + 16777216); // 16 MB

    float* ws = (float*)d_ws;
    float* pa = ws;                              // 32*16384
    float* pkn = pa + (size_t)NSLOT * Mq_;
    float* pcn = pkn + (size_t)NSLOT * Mq_;
    float* probs = pcn + (size_t)NSLOT * Mq_;    // 16384
    float* w = probs + Mq_;                      // 2048
    float* c0 = w + DQK_;                        // 4
    float* snorm = c0 + 4;                       // 4
    float* pprob = snorm + 4;                    // 16384
    int* posArr = (int*)(pprob + Mq_);           // 16384
    int* cid = posArr + Mq_;                     // 16384
    int* nch = cid + Mq_;                        // 8
    float* hseg = (float*)(nch + 8);             // 4*16*2048
    float* segGate = hseg + Bq_ * NSEG * Dq_;    // 64
    float* carryArr = segGate + 64;              // 4*16*2048

    split_kernel<<<2048, 256, 0, stream>>>(tokens, Thi, Tlo, Mq_ * Dq_ / 4);
    wsplitT_kernel<<<dim3(32, 64), 256, 0, stream>>>(W, WhiT, WloT);
    wqs_kernel<<<DQK_, 256, 0, stream>>>(W, s, w);
    l0_kernel<<<Bq_ + 1, 256, 0, stream>>>(tokens, s, w, c0, snorm);

    hipFuncSetAttribute(reinterpret_cast<const void*>(gemm_kernel),
                        hipFuncAttributeMaxDynamicSharedMemorySize, BUFSZ);
    gemm_kernel<<<1024, 512, BUFSZ, stream>>>(Thi, Tlo, WhiT, WloT, pa, pkn, pcn);

    rowstat_kernel<<<Mq_ / 256, 256, 0, stream>>>(pa, pkn, pcn, c0, snorm, probs);
    pack_kernel<<<Bq_, 256, 0, stream>>>(probs, posArr, pprob, cid, nch, out_aux);
    segend_kernel<<<dim3(8, NSEG, Bq_), 256, 0, stream>>>(tokens, posArr, pprob, hseg, segGate);
    carry_kernel<<<32, 256, 0, stream>>>(hseg, segGate, carryArr);
    scan3_kernel<<<dim3(8, NSEG, Bq_), 256, 0, stream>>>(tokens, posArr, pprob, carryArr, out_sm);
    upsample_kernel<<<Mq_, 256, 0, stream>>>(out_sm, cid, out_up);
}

// Round 16
// 748.009 us; speedup vs baseline: 5.7079x; 5.7079x over previous
//
#include <hip/hip_runtime.h>
#include <math.h>

#define Bq_ 4
#define Lq_ 4096
#define Dq_ 2048
#define Mq_ 16384
#define NW_ 4096
#define DQK_ 2048
#define NSLOT 32
#define BM_ 256
#define BN_ 128
#define NSEG 16
#define SEGLEN 256
#define BUFSZ 66560    // A 264*128 + B 256*128
#define BOFF_ 33792

typedef short s8v __attribute__((ext_vector_type(8)));
typedef float f4v __attribute__((ext_vector_type(4)));

#define GLDS16(g, l) __builtin_amdgcn_global_load_lds( \
    (const __attribute__((address_space(1))) unsigned int*)(g), \
    (__attribute__((address_space(3))) unsigned int*)(l), 16, 0, 0)

__device__ __forceinline__ void bf16split(float x, unsigned short& h, unsigned short& l) {
    unsigned u = __float_as_uint(x);
    unsigned hb = (u + 0x7FFFu + ((u >> 16) & 1u)) & 0xFFFF0000u;
    float fh = __uint_as_float(hb);
    float r = x - fh;
    unsigned ur = __float_as_uint(r);
    unsigned lb = (ur + 0x7FFFu + ((ur >> 16) & 1u)) >> 16;
    h = (unsigned short)(hb >> 16);
    l = (unsigned short)lb;
}

// ---------------------------------------------------------------------------
__global__ __launch_bounds__(256) void split_kernel(const float* __restrict__ in,
                                                    unsigned short* __restrict__ hi,
                                                    unsigned short* __restrict__ lo,
                                                    int n4) {
    int stride = gridDim.x * 256;
    for (int i = blockIdx.x * 256 + threadIdx.x; i < n4; i += stride) {
        float4 v = ((const float4*)in)[i];
        float vv[4] = {v.x, v.y, v.z, v.w};
        unsigned short hh[4], ll[4];
#pragma unroll
        for (int j = 0; j < 4; ++j) bf16split(vv[j], hh[j], ll[j]);
        ushort4 h4 = make_ushort4(hh[0], hh[1], hh[2], hh[3]);
        ushort4 l4 = make_ushort4(ll[0], ll[1], ll[2], ll[3]);
        ((ushort4*)hi)[i] = h4;
        ((ushort4*)lo)[i] = l4;
    }
}

// W [2048][4096] f32 -> WhiT/WloT [4096][2048] bf16 (transposed + split)
__global__ __launch_bounds__(256) void wsplitT_kernel(const float* __restrict__ W,
                                                      unsigned short* __restrict__ hiT,
                                                      unsigned short* __restrict__ loT) {
    __shared__ float tile[64][65];
    int k0 = blockIdx.x * 64, n0 = blockIdx.y * 64;
    int tid = threadIdx.x;
#pragma unroll
    for (int e = 0; e < 16; ++e) {
        int idx = e * 256 + tid;
        int r = idx >> 6, j = idx & 63;
        tile[r][j] = W[(size_t)(k0 + r) * NW_ + n0 + j];
    }
    __syncthreads();
#pragma unroll
    for (int e = 0; e < 16; ++e) {
        int idx = e * 256 + tid;
        int nn = idx >> 6, kk = idx & 63;
        unsigned short h, l;
        bf16split(tile[kk][nn], h, l);
        size_t o = (size_t)(n0 + nn) * DQK_ + k0 + kk;
        hiT[o] = h;
        loT[o] = l;
    }
}

// ---------------------------------------------------------------------------
__global__ __launch_bounds__(256) void wqs_kernel(const float* __restrict__ W,
                                                  const float* __restrict__ s,
                                                  float* __restrict__ w) {
    int d = blockIdx.x;
    int tid = threadIdx.x;
    float acc = 0.f;
    const float* row = W + (size_t)d * NW_;
    for (int j = tid; j < DQK_; j += 256) acc += row[j] * s[j];
    __shared__ float red[256];
    red[tid] = acc;
    __syncthreads();
    for (int off = 128; off > 0; off >>= 1) {
        if (tid < off) red[tid] += red[tid + off];
        __syncthreads();
    }
    if (tid == 0) w[d] = red[0];
}

__global__ __launch_bounds__(256) void l0_kernel(const float* __restrict__ tokens,
                                                 const float* __restrict__ s,
                                                 const float* __restrict__ w,
                                                 float* __restrict__ c0,
                                                 float* __restrict__ snorm) {
    int b = blockIdx.x;
    int tid = threadIdx.x;
    float acc = 0.f;
    if (b < Bq_) {
        const float* t = tokens + (size_t)b * Lq_ * Dq_;
        for (int dd = tid; dd < Dq_; dd += 256) acc += t[dd] * w[dd];
    } else {
        for (int jj = tid; jj < DQK_; jj += 256) acc += s[jj] * s[jj];
    }
    __shared__ float red[256];
    red[tid] = acc;
    __syncthreads();
    for (int off = 128; off > 0; off >>= 1) {
        if (tid < off) red[tid] += red[tid + off];
        __syncthreads();
    }
    if (tid == 0) {
        if (b < Bq_) c0[b] = red[0];
        else snorm[0] = red[0];
    }
}

// ---------------------------------------------------------------------------
// bf16x3 MFMA GEMM (256x128, full K, BK=32, hi|lo-packed rows, double-buffered
// LDS 2-phase pipeline) fused with per-row reductions.
// id = mt*16 + nt : XCD x owns nt in {x, x+8}.
__global__ __launch_bounds__(512, 2) void gemm_kernel(const unsigned short* __restrict__ Thi,
                                                      const unsigned short* __restrict__ Tlo,
                                                      const unsigned short* __restrict__ Whi,
                                                      const unsigned short* __restrict__ Wlo,
                                                      float* __restrict__ pa,
                                                      float* __restrict__ pkn,
                                                      float* __restrict__ pcn) {
    extern __shared__ char smc[];

    int id = blockIdx.x;
    int nt = id & 15;
    int mt = id >> 4;
    int r0 = mt * BM_;
    int c0 = nt * BN_;
    int tid = threadIdx.x;
    int lane = tid & 63, w = tid >> 6;
    int wm = w >> 1, wn = w & 1;
    int lr = lane & 15, lg = lane >> 4;

    // ---- staging addresses (row = 128B = [hi 32bf16 | lo 32bf16], XOR chunk swz)
    int rl = tid >> 3;            // row within 64-row call block
    int ch = tid & 7;             // phys chunk
    int s = ch ^ (rl & 7);        // logical source chunk
    const unsigned short* aptr = (s < 4) ? Thi : Tlo;
    const unsigned short* bptr = (s < 4) ? Whi : Wlo;
    int ako = (s & 3) * 8;
    int aoff[4], boff[4];
#pragma unroll
    for (int i = 0; i < 4; ++i) {
        int g = r0 - 1 + i * 64 + rl;
        g = g < 0 ? 0 : (g > Mq_ - 1 ? Mq_ - 1 : g);
        aoff[i] = g * Dq_ + ako;
    }
#pragma unroll
    for (int i = 0; i < 4; ++i) {
        int j = i * 64 + rl;
        int wr = j < 128 ? c0 + j : DQK_ + c0 + (j - 128);
        boff[i] = wr * DQK_ + ako;
    }
    // partial A call (rows 256..263, wave 0 only)
    int rlX = 256 + (lane >> 3);
    int sX = (lane & 7) ^ ((lane >> 3) & 7);
    const unsigned short* aptrX = (sX < 4) ? Thi : Tlo;
    int gX = r0 - 1 + rlX;
    gX = gX > Mq_ - 1 ? Mq_ - 1 : gX;
    int aoffX = gX * Dq_ + (sX & 3) * 8;

    // ---- ds read byte-offsets (hi; lo = ^64)
    int aq_ad[4], ak_ad[4], bq_ad[4], bk_ad[4];
#pragma unroll
    for (int rf = 0; rf < 4; ++rf) {
        int rq = wm * 64 + rf * 16 + lr + 1;
        int rk = rq - 1;
        aq_ad[rf] = rq * 128 + ((lg ^ (rq & 7)) * 16);
        ak_ad[rf] = rk * 128 + ((lg ^ (rk & 7)) * 16);
    }
#pragma unroll
    for (int cf = 0; cf < 4; ++cf) {
        int rbq = wn * 64 + cf * 16 + lr;
        int rbk = rbq + 128;
        bq_ad[cf] = rbq * 128 + ((lg ^ (rbq & 7)) * 16);
        bk_ad[cf] = rbk * 128 + ((lg ^ (rbk & 7)) * 16);
    }

    f4v accq[4][4], acck[4][4];
#pragma unroll
    for (int rf = 0; rf < 4; ++rf)
#pragma unroll
        for (int cf = 0; cf < 4; ++cf) {
            accq[rf][cf] = (f4v){0.f, 0.f, 0.f, 0.f};
            acck[rf][cf] = (f4v){0.f, 0.f, 0.f, 0.f};
        }

#define STAGE(buf, k0e)                                                     \
    {                                                                       \
        char* bA = smc + (buf) * BUFSZ;                                     \
        char* bB = bA + BOFF_;                                              \
        _Pragma("unroll")                                                   \
        for (int i = 0; i < 4; ++i)                                         \
            GLDS16(aptr + aoff[i] + (k0e), bA + (i * 64 + w * 8) * 128);    \
        if (w == 0)                                                         \
            GLDS16(aptrX + aoffX + (k0e), bA + 256 * 128);                  \
        _Pragma("unroll")                                                   \
        for (int i = 0; i < 4; ++i)                                         \
            GLDS16(bptr + boff[i] + (k0e), bB + (i * 64 + w * 8) * 128);    \
    }

    int cur = 0;
    STAGE(0, 0);
    __syncthreads();

    for (int kt = 0; kt < 64; ++kt) {
        if (kt < 63) STAGE(cur ^ 1, (kt + 1) * 32);

        const char* bA = smc + cur * BUFSZ;
        const char* bB = bA + BOFF_;
        s8v aqh[4], aql[4], akh[4], akl[4];
#pragma unroll
        for (int rf = 0; rf < 4; ++rf) {
            aqh[rf] = *(const s8v*)(bA + aq_ad[rf]);
            aql[rf] = *(const s8v*)(bA + (aq_ad[rf] ^ 64));
            akh[rf] = *(const s8v*)(bA + ak_ad[rf]);
            akl[rf] = *(const s8v*)(bA + (ak_ad[rf] ^ 64));
        }
#pragma unroll
        for (int cf = 0; cf < 4; ++cf) {
            s8v bqh = *(const s8v*)(bB + bq_ad[cf]);
            s8v bql = *(const s8v*)(bB + (bq_ad[cf] ^ 64));
            s8v bkh = *(const s8v*)(bB + bk_ad[cf]);
            s8v bkl = *(const s8v*)(bB + (bk_ad[cf] ^ 64));
#pragma unroll
            for (int rf = 0; rf < 4; ++rf) {
                accq[rf][cf] = __builtin_amdgcn_mfma_f32_16x16x32_bf16(aqh[rf], bqh, accq[rf][cf], 0, 0, 0);
                accq[rf][cf] = __builtin_amdgcn_mfma_f32_16x16x32_bf16(aqh[rf], bql, accq[rf][cf], 0, 0, 0);
                accq[rf][cf] = __builtin_amdgcn_mfma_f32_16x16x32_bf16(aql[rf], bqh, accq[rf][cf], 0, 0, 0);
                acck[rf][cf] = __builtin_amdgcn_mfma_f32_16x16x32_bf16(akh[rf], bkh, acck[rf][cf], 0, 0, 0);
                acck[rf][cf] = __builtin_amdgcn_mfma_f32_16x16x32_bf16(akh[rf], bkl, acck[rf][cf], 0, 0, 0);
                acck[rf][cf] = __builtin_amdgcn_mfma_f32_16x16x32_bf16(akl[rf], bkh, acck[rf][cf], 0, 0, 0);
            }
        }
        __syncthreads();
        cur ^= 1;
    }
#undef STAGE

    size_t o = (size_t)(nt * 2 + wn) * Mq_;
#pragma unroll
    for (int rf = 0; rf < 4; ++rf) {
        int rbase = r0 + wm * 64 + rf * 16 + lg * 4;
#pragma unroll
        for (int jj = 0; jj < 4; ++jj) {
            float sq = 0.f, sk = 0.f, sc = 0.f;
#pragma unroll
            for (int cf = 0; cf < 4; ++cf) {
                float q = accq[rf][cf][jj];
                float k = acck[rf][cf][jj];
                sq = fmaf(q, q, sq);
                sk = fmaf(k, k, sk);
                sc = fmaf(q, k, sc);
            }
#pragma unroll
            for (int m = 1; m < 16; m <<= 1) {
                sq += __shfl_xor(sq, m);
                sk += __shfl_xor(sk, m);
                sc += __shfl_xor(sc, m);
            }
            if (lr == 0) {
                int r = rbase + jj;
                pa[o + r] = sq;   // ||q_r||^2 partial
                pcn[o + r] = sc;  // q_r . k_{r-1} partial
                pkn[o + r] = sk;  // ||k_{r-1}||^2 partial
            }
        }
    }
}

// ---------------------------------------------------------------------------
__global__ __launch_bounds__(256) void rowstat_kernel(const float* __restrict__ pa,
                                                      const float* __restrict__ pkn,
                                                      const float* __restrict__ pcn,
                                                      const float* __restrict__ c0,
                                                      const float* __restrict__ snorm,
                                                      float* __restrict__ probs) {
    int r = blockIdx.x * 256 + threadIdx.x;
    float a = 0.f, bb = 0.f, c = 0.f;
    for (int s = 0; s < NSLOT; ++s) {
        size_t o = (size_t)s * Mq_;
        a += pa[o + r];
        c += pcn[o + r];
        bb += pkn[o + r];
    }
    if ((r & (Lq_ - 1)) == 0) { c = c0[r >> 12]; bb = snorm[0]; }
    float na = fmaxf(sqrtf(a), 1e-8f);
    float nb = fmaxf(sqrtf(bb), 1e-8f);
    float cosv = c / (na * nb);
    probs[r] = (1.f - cosv) * 0.5f;
}

// ---------------------------------------------------------------------------
__global__ __launch_bounds__(256) void pack_kernel(const float* __restrict__ probs,
                                                   int* __restrict__ posArr,
                                                   float* __restrict__ pprob,
                                                   int* __restrict__ cid,
                                                   int* __restrict__ nch,
                                                   float* __restrict__ aux) {
    int b = blockIdx.x;
    int tid = threadIdx.x;
    int base = b * Lq_ + tid * 16;
#pragma unroll
    for (int u = 0; u < 16; ++u) {
        posArr[base + u] = 0;
        pprob[base + u] = 0.f;
    }
    float p[16];
    bool bd[16];
    int c = 0;
#pragma unroll
    for (int u = 0; u < 16; ++u) {
        p[u] = probs[base + u];
        bd[u] = (p[u] > 0.5f) || (tid == 0 && u == 0);
        c += bd[u] ? 1 : 0;
    }
    __shared__ int sc[256];
    sc[tid] = c;
    __syncthreads();
    for (int off = 1; off < 256; off <<= 1) {
        int t = (tid >= off) ? sc[tid - off] : 0;
        __syncthreads();
        sc[tid] += t;
        __syncthreads();
    }
    int idx = sc[tid] - c;
#pragma unroll
    for (int u = 0; u < 16; ++u) {
        if (bd[u]) {
            posArr[b * Lq_ + idx] = tid * 16 + u;
            pprob[b * Lq_ + idx] = p[u];
            idx++;
        }
        cid[base + u] = idx - 1;
    }
    if (tid == 255) nch[b] = sc[255];
    if (b == 0 && tid == 0) aux[0] = 0.0f;
}

// ---------------------------------------------------------------------------
// Segmented gated scan, pass 1: per-segment end state + segment gate product
__global__ __launch_bounds__(256) void segend_kernel(const float* __restrict__ tokens,
                                                     const int* __restrict__ posArr,
                                                     const float* __restrict__ pprob,
                                                     float* __restrict__ hseg,
                                                     float* __restrict__ segGate) {
    int b = blockIdx.z, s = blockIdx.y;
    int ch = blockIdx.x * 256 + threadIdx.x;
    const float* tb = tokens + (size_t)b * Lq_ * Dq_ + ch;
    const int* pos = posArr + b * Lq_ + s * SEGLEN;
    const float* pp = pprob + b * Lq_ + s * SEGLEN;
    float h = 0.f;
    for (int u = 0; u < SEGLEN; ++u) {
        float pv = pp[u];
        int t0 = pos[u];
        h = fmaf(1.f - pv, h, tb[(size_t)t0 * Dq_] * pv);
    }
    hseg[((size_t)b * NSEG + s) * Dq_ + ch] = h;
    __shared__ float g_[256];
    if (blockIdx.x == 0) {
        g_[threadIdx.x] = 1.f - pp[threadIdx.x];
        __syncthreads();
        if (threadIdx.x == 0) {
            float P = 1.f;
            for (int i = 0; i < 256; ++i) P *= g_[i];
            segGate[b * NSEG + s] = P;
        }
    }
}

// pass 2: sequential carry combine across segments
__global__ __launch_bounds__(256) void carry_kernel(const float* __restrict__ hseg,
                                                    const float* __restrict__ segGate,
                                                    float* __restrict__ carryArr) {
    int idx = blockIdx.x * 256 + threadIdx.x;  // 0..8191
    int b = idx >> 11;
    int ch = idx & 2047;
    float carry = 0.f;
#pragma unroll
    for (int s = 0; s < NSEG; ++s) {
        size_t o = ((size_t)b * NSEG + s) * Dq_ + ch;
        carryArr[o] = carry;
        carry = hseg[o] + carry * segGate[b * NSEG + s];
    }
}

// pass 3: re-scan with carry-in, write smoothed
__global__ __launch_bounds__(256) void scan3_kernel(const float* __restrict__ tokens,
                                                    const int* __restrict__ posArr,
                                                    const float* __restrict__ pprob,
                                                    const float* __restrict__ carryArr,
                                                    float* __restrict__ out_sm) {
    int b = blockIdx.z, s = blockIdx.y;
    int ch = blockIdx.x * 256 + threadIdx.x;
    const float* tb = tokens + (size_t)b * Lq_ * Dq_ + ch;
    const int* pos = posArr + b * Lq_ + s * SEGLEN;
    const float* pp = pprob + b * Lq_ + s * SEGLEN;
    float* sm = out_sm + (size_t)b * Lq_ * Dq_ + (size_t)s * SEGLEN * Dq_ + ch;
    float h = carryArr[((size_t)b * NSEG + s) * Dq_ + ch];
    for (int u = 0; u < SEGLEN; ++u) {
        float pv = pp[u];
        int t0 = pos[u];
        h = fmaf(1.f - pv, h, tb[(size_t)t0 * Dq_] * pv);
        sm[(size_t)u * Dq_] = h;
    }
}

// ---------------------------------------------------------------------------
__global__ __launch_bounds__(256) void upsample_kernel(const float* __restrict__ sm,
                                                       const int* __restrict__ cid,
                                                       float* __restrict__ up) {
    int r = blockIdx.x;
    int b = r >> 12;
    int c = cid[r];
    const float* src = sm + ((size_t)b * Lq_ + c) * Dq_;
    float* dst = up + (size_t)r * Dq_;
    int tid = threadIdx.x;
    *(float4*)&dst[tid * 8] = *(const float4*)&src[tid * 8];
    *(float4*)&dst[tid * 8 + 4] = *(const float4*)&src[tid * 8 + 4];
}

// ---------------------------------------------------------------------------
extern "C" void kernel_launch(void* const* d_in, const int* in_sizes, int n_in,
                              void* d_out, int out_size, void* d_ws, size_t ws_size,
                              hipStream_t stream) {
    const float* tokens = (const float*)d_in[0];
    const float* W = (const float*)d_in[1];
    const float* s = (const float*)d_in[2];

    float* out = (float*)d_out;
    float* out_sm = out;
    float* out_up = out + (size_t)Mq_ * Dq_;
    float* out_aux = out + 2 * (size_t)Mq_ * Dq_;

    // bf16 staging buffers live inside d_out (overwritten by final outputs later)
    unsigned short* Thi = (unsigned short*)out_up;                      // 64 MB
    unsigned short* Tlo = (unsigned short*)((char*)out_up + 67108864);  // 64 MB
    unsigned short* WhiT = (unsigned short*)out_sm;                     // 16 MB
    unsigned short* WloT = (unsigned short*)((char*)out_sm + 16777216); // 16 MB

    float* ws = (float*)d_ws;
    float* pa = ws;                              // 32*16384
    float* pkn = pa + (size_t)NSLOT * Mq_;
    float* pcn = pkn + (size_t)NSLOT * Mq_;
    float* probs = pcn + (size_t)NSLOT * Mq_;    // 16384
    float* w = probs + Mq_;                      // 2048
    float* c0 = w + DQK_;                        // 4
    float* snorm = c0 + 4;                       // 4
    float* pprob = snorm + 4;                    // 16384
    int* posArr = (int*)(pprob + Mq_);           // 16384
    int* cid = posArr + Mq_;                     // 16384
    int* nch = cid + Mq_;                        // 8
    float* hseg = (float*)(nch + 8);             // 4*16*2048
    float* segGate = hseg + Bq_ * NSEG * Dq_;    // 64
    float* carryArr = segGate + 64;              // 4*16*2048

    split_kernel<<<2048, 256, 0, stream>>>(tokens, Thi, Tlo, Mq_ * Dq_ / 4);
    wsplitT_kernel<<<dim3(32, 64), 256, 0, stream>>>(W, WhiT, WloT);
    wqs_kernel<<<DQK_, 256, 0, stream>>>(W, s, w);
    l0_kernel<<<Bq_ + 1, 256, 0, stream>>>(tokens, s, w, c0, snorm);

    hipFuncSetAttribute(reinterpret_cast<const void*>(gemm_kernel),
                        hipFuncAttributeMaxDynamicSharedMemorySize, 2 * BUFSZ);
    gemm_kernel<<<1024, 512, 2 * BUFSZ, stream>>>(Thi, Tlo, WhiT, WloT, pa, pkn, pcn);

    rowstat_kernel<<<Mq_ / 256, 256, 0, stream>>>(pa, pkn, pcn, c0, snorm, probs);
    pack_kernel<<<Bq_, 256, 0, stream>>>(probs, posArr, pprob, cid, nch, out_aux);
    segend_kernel<<<dim3(8, NSEG, Bq_), 256, 0, stream>>>(tokens, posArr, pprob, hseg, segGate);
    carry_kernel<<<32, 256, 0, stream>>>(hseg, segGate, carryArr);
    scan3_kernel<<<dim3(8, NSEG, Bq_), 256, 0, stream>>>(tokens, posArr, pprob, carryArr, out_sm);
    upsample_kernel<<<Mq_, 256, 0, stream>>>(out_sm, cid, out_up);
}